// Round 3
// baseline (1843.119 us; speedup 1.0000x reference)
//
#include <hip/hip_runtime.h>
#include <stdint.h>

#define NIMG 8
#define HFW  64
#define HWA  36864     // 64*64*9
#define PRE  2000
#define POST 300

__device__ __forceinline__ unsigned keyOf(float f) {
    unsigned u = __float_as_uint(f);
    return (u & 0x80000000u) ? ~u : (u | 0x80000000u);
}
__device__ __forceinline__ unsigned umin2(unsigned a, unsigned b){ return a < b ? a : b; }

// ---------------------------------------------------------------------------
// K0: w_conv [co][ci][3][3] -> wt2 [ci][ky][cog(32)][co_l(8)*3+kx]  (24 f/group)
// ---------------------------------------------------------------------------
__global__ void prep_wt2(const float* __restrict__ w, float* __restrict__ wt2) {
    int t = blockIdx.x * 256 + threadIdx.x;      // t = (ci*3+ky)*256 + co
    if (t >= 256 * 3 * 256) return;
    int co = t & 255;
    int r  = t >> 8;            // ci*3+ky
    int ky = r % 3, ci = r / 3;
    const float* s = w + ((size_t)(co * 256 + ci)) * 9 + ky * 3;
    float* d = wt2 + (((size_t)(ci * 3 + ky)) * 32 + (co >> 3)) * 24 + (co & 7) * 3;
    d[0] = s[0]; d[1] = s[1]; d[2] = s[2];
}

// ---------------------------------------------------------------------------
// K1 v2: 3x3 conv SAME + bias + relu.  fp32 VALU, scalar-path weights.
// block 256 thr; tile 8co x 16rows x 64px; thread 8co x 4px (32 acc).
// grid (32 cog, 4 strip, 8 n) = 1024 blocks -> 4 blocks/CU, 16 waves/CU.
// LDS: features only, double-buffered, cols stored SHIFTED +1 (idx j+1 = col j,
// idx 0 = col -1 = 0, idx 65 = col 64 = 0) so the 6-col window is 2x b128.
// ---------------------------------------------------------------------------
__global__ __launch_bounds__(256, 4) void conv3x3_relu_v2(const float* __restrict__ feat,
        const float* __restrict__ wt2, const float* __restrict__ bconv,
        float* __restrict__ h)
{
    __shared__ float sAll[2 * 4 * 18 * 68];      // 2 x 19,584 B = 39,168 B

    const int tid = threadIdx.x;
    const int cog = blockIdx.x;          // 0..31
    const int y0  = blockIdx.y * 16;     // 0,16,32,48
    const int n   = blockIdx.z;          // 0..7
    const int pg  = tid & 15;
    const int px  = pg * 4;
    const int rr  = tid >> 4;            // 0..15

    const float* fb = feat + (size_t)n * 1048576;

    // one-time halo zeros (idx 0 and 65 of every row, both buffers)
    for (int j = tid; j < 288; j += 256) {
        const int b = j / 144, rem = j % 144;
        const int i = rem / 36, q2 = rem % 36, r = q2 >> 1, c = (q2 & 1) * 65;
        sAll[b * 4896 + (i * 18 + r) * 68 + c] = 0.0f;
    }

    float acc[8][4];
#pragma unroll
    for (int a = 0; a < 8; a++)
#pragma unroll
        for (int b = 0; b < 4; b++) acc[a][b] = 0.0f;

    // task t (0..1151): i = t/288, r = (t%288)/16, q = t%16 -> cols q*4..q*4+3
#define LD_TASK(T, CI0, DST) {                                              \
        const int _t = (T);                                                 \
        const int _i = _t / 288, _rm = _t % 288;                            \
        const int _r = _rm >> 4, _q = _rm & 15;                             \
        const int _gy = y0 - 1 + _r;                                        \
        float4 _v = {0.f, 0.f, 0.f, 0.f};                                   \
        if (_gy >= 0 && _gy < 64)                                           \
            _v = *(const float4*)(fb + (size_t)((CI0) + _i) * 4096 + _gy * 64 + _q * 4); \
        DST = _v; }

#define ST_TASK(T, BUF, V) {                                                \
        const int _t = (T);                                                 \
        const int _i = _t / 288, _rm = _t % 288;                            \
        const int _r = _rm >> 4, _q = _rm & 15;                             \
        float* _p = (BUF) + (_i * 18 + _r) * 68 + _q * 4 + 1;               \
        _p[0] = (V).x; *(float2*)(_p + 1) = make_float2((V).y, (V).z);      \
        _p[3] = (V).w; }

    // prologue: stage ck = 0 into buffer 0
    {
        float4 s0, s1, s2, s3, s4;
        LD_TASK(tid,        0, s0); LD_TASK(tid + 256, 0, s1);
        LD_TASK(tid + 512,  0, s2); LD_TASK(tid + 768, 0, s3);
        if (tid < 128) { LD_TASK(tid + 1024, 0, s4); }
        float* b0 = sAll;
        ST_TASK(tid,       b0, s0); ST_TASK(tid + 256, b0, s1);
        ST_TASK(tid + 512, b0, s2); ST_TASK(tid + 768, b0, s3);
        if (tid < 128) { ST_TASK(tid + 1024, b0, s4); }
    }
    __syncthreads();

    for (int ck = 0; ck < 64; ck++) {
        const int ci0 = ck * 4;
        const float* bufc = sAll + (ck & 1) * 4896;
        float*       bufn = sAll + ((ck + 1) & 1) * 4896;

        // issue next-ck global loads early (hide under compute)
        float4 s0, s1, s2, s3, s4;
        if (ck < 63) {
            const int nci0 = ci0 + 4;
            LD_TASK(tid,        nci0, s0); LD_TASK(tid + 256, nci0, s1);
            LD_TASK(tid + 512,  nci0, s2); LD_TASK(tid + 768, nci0, s3);
            if (tid < 128) { LD_TASK(tid + 1024, nci0, s4); }
        }

        // compute: 12 (i,ky) steps x (2 ds_read_b128 + 24 scalar weights + 96 fmac)
        const float* rbase = bufc + rr * 68 + px;
#pragma unroll
        for (int i = 0; i < 4; i++) {
#pragma unroll
            for (int ky = 0; ky < 3; ky++) {
                const float* rowp = rbase + (i * 18 + ky) * 68;
                const float4 fA = *(const float4*)rowp;        // cols px-1..px+2
                const float4 fB = *(const float4*)(rowp + 4);  // cols px+3..px+6
                const float fc0 = fA.x, fc1 = fA.y, fc2 = fA.z, fc3 = fA.w;
                const float fc4 = fB.x, fc5 = fB.y;
                const float* wq = wt2 + (((size_t)(ci0 + i) * 3 + ky) * 32 + cog) * 24;
#pragma unroll
                for (int cc = 0; cc < 8; cc++) {
                    const float w0 = wq[cc * 3 + 0], w1 = wq[cc * 3 + 1], w2 = wq[cc * 3 + 2];
                    acc[cc][0] = fmaf(w0, fc0, acc[cc][0]);
                    acc[cc][0] = fmaf(w1, fc1, acc[cc][0]);
                    acc[cc][0] = fmaf(w2, fc2, acc[cc][0]);
                    acc[cc][1] = fmaf(w0, fc1, acc[cc][1]);
                    acc[cc][1] = fmaf(w1, fc2, acc[cc][1]);
                    acc[cc][1] = fmaf(w2, fc3, acc[cc][1]);
                    acc[cc][2] = fmaf(w0, fc2, acc[cc][2]);
                    acc[cc][2] = fmaf(w1, fc3, acc[cc][2]);
                    acc[cc][2] = fmaf(w2, fc4, acc[cc][2]);
                    acc[cc][3] = fmaf(w0, fc3, acc[cc][3]);
                    acc[cc][3] = fmaf(w1, fc4, acc[cc][3]);
                    acc[cc][3] = fmaf(w2, fc5, acc[cc][3]);
                }
            }
        }

        if (ck < 63) {
            ST_TASK(tid,       bufn, s0); ST_TASK(tid + 256, bufn, s1);
            ST_TASK(tid + 512, bufn, s2); ST_TASK(tid + 768, bufn, s3);
            if (tid < 128) { ST_TASK(tid + 1024, bufn, s4); }
        }
        __syncthreads();
    }

    // epilogue: bias + relu + store (rows contiguous per wave -> coalesced)
#pragma unroll
    for (int cc = 0; cc < 8; cc++) {
        const int co = cog * 8 + cc;
        const float b = bconv[co];
        float4 o;
        o.x = fmaxf(acc[cc][0] + b, 0.f);
        o.y = fmaxf(acc[cc][1] + b, 0.f);
        o.z = fmaxf(acc[cc][2] + b, 0.f);
        o.w = fmaxf(acc[cc][3] + b, 0.f);
        *(float4*)(h + ((size_t)(n * 256 + co)) * 4096 + (y0 + rr) * 64 + px) = o;
    }
#undef LD_TASK
#undef ST_TASK
}

// ---------------------------------------------------------------------------
// K2: 1x1 heads (scores 9, locs 36) + box decode + clip + validity -> keys/rois
// ---------------------------------------------------------------------------
__global__ __launch_bounds__(256) void head_decode(const float* __restrict__ h,
        const float* __restrict__ wsc, const float* __restrict__ bsc,
        const float* __restrict__ wlc, const float* __restrict__ blc,
        unsigned* __restrict__ keys, float* __restrict__ rois)
{
    __shared__ float sH[128][64];
    __shared__ float sOut[64][49];

    const int tid = threadIdx.x;
    const int y   = blockIdx.x;
    const int n   = blockIdx.y;
    const int px  = tid & 63;
    const int sl  = tid >> 6;             // == wave id
    const int o0  = sl * 12;

    const float* wp[12];
#pragma unroll
    for (int j = 0; j < 12; j++) {
        const int o = o0 + j;
        wp[j] = (o < 36) ? (wlc + (size_t)o * 256)
                         : ((o < 45) ? (wsc + (size_t)(o - 36) * 256) : wsc);
    }
    float r[12];
#pragma unroll
    for (int j = 0; j < 12; j++) r[j] = 0.0f;

    const float* hb = h + (size_t)n * 1048576 + y * 64;
    for (int half = 0; half < 2; half++) {
        for (int task = tid; task < 2048; task += 256) {
            const int c = task >> 4, x4 = (task & 15) << 2;
            *(float4*)&sH[c][x4] =
                *(const float4*)(hb + (size_t)(half * 128 + c) * 4096 + x4);
        }
        __syncthreads();
        for (int c4 = 0; c4 < 128; c4 += 4) {
            const float h0 = sH[c4][px], h1 = sH[c4 + 1][px];
            const float h2 = sH[c4 + 2][px], h3 = sH[c4 + 3][px];
#pragma unroll
            for (int j = 0; j < 12; j++) {
                float4 w = *(const float4*)(wp[j] + half * 128 + c4);
                r[j] = fmaf(h0, w.x, r[j]); r[j] = fmaf(h1, w.y, r[j]);
                r[j] = fmaf(h2, w.z, r[j]); r[j] = fmaf(h3, w.w, r[j]);
            }
        }
        __syncthreads();
    }
#pragma unroll
    for (int j = 0; j < 12; j++) {
        const int o = o0 + j;
        if (o < 45) {
            const float bias = (o < 36) ? blc[o] : bsc[o - 36];
            sOut[px][o] = r[j] + bias;
        }
    }
    __syncthreads();

    // decode (replicate reference fp32 op order; no contraction)
    for (int a = sl; a < 9; a += 4) {
        const float s  = sOut[px][36 + a];
        const float dy = sOut[px][a * 4 + 0], dx = sOut[px][a * 4 + 1];
        const float dh = sOut[px][a * 4 + 2], dw = sOut[px][a * 4 + 3];
        const int si = a / 3, ri = a - si * 3;
        const float scale = (si == 0) ? 64.f : ((si == 1) ? 128.f : 256.f);
        const float rat   = (ri == 0) ? 0.5f : ((ri == 1) ? 1.f : 2.f);
        const float sq = __fsqrt_rn(rat);
        const float hs = __fmul_rn(scale, sq);
        const float ws = __fdiv_rn(scale, sq);
        const float cy = (y  + 0.5f) * 16.0f;   // exact
        const float cx = (px + 0.5f) * 16.0f;
        const float y1 = __fsub_rn(cy, __fmul_rn(hs, 0.5f));
        const float x1 = __fsub_rn(cx, __fmul_rn(ws, 0.5f));
        const float y2 = __fadd_rn(cy, __fmul_rn(hs, 0.5f));
        const float x2 = __fadd_rn(cx, __fmul_rn(ws, 0.5f));
        const float ah = __fsub_rn(y2, y1), aw = __fsub_rn(x2, x1);
        const float acy = __fadd_rn(y1, __fmul_rn(0.5f, ah));
        const float acx = __fadd_rn(x1, __fmul_rn(0.5f, aw));
        const float pcy = __fadd_rn(__fmul_rn(dy, ah), acy);
        const float pcx = __fadd_rn(__fmul_rn(dx, aw), acx);
        const float ph  = __fmul_rn(expf(dh), ah);
        const float pw  = __fmul_rn(expf(dw), aw);
        float by1 = __fsub_rn(pcy, __fmul_rn(0.5f, ph));
        float bx1 = __fsub_rn(pcx, __fmul_rn(0.5f, pw));
        float by2 = __fadd_rn(pcy, __fmul_rn(0.5f, ph));
        float bx2 = __fadd_rn(pcx, __fmul_rn(0.5f, pw));
        by1 = fminf(fmaxf(by1, 0.f), 1024.f); by2 = fminf(fmaxf(by2, 0.f), 1024.f);
        bx1 = fminf(fmaxf(bx1, 0.f), 1024.f); bx2 = fminf(fmaxf(bx2, 0.f), 1024.f);
        const float bh = __fsub_rn(by2, by1), bw = __fsub_rn(bx2, bx1);
        const bool valid = (bh >= 16.f) && (bw >= 16.f) && (s >= 0.f);
        const float sm = valid ? s : -1e9f;
        const int idx = (y * 64 + px) * 9 + a;
        keys[(size_t)n * HWA + idx] = keyOf(sm);
        float4 bxv = {by1, bx1, by2, bx2};
        *(float4*)&rois[((size_t)n * HWA + idx) * 4] = bxv;
    }
}

// ---------------------------------------------------------------------------
// K3: exact top-2000 sorted (key desc, idx asc) via 3-level histogram select
//     + compaction + 2048 bitonic sort.  1 block (1024 thr) per image.
// ---------------------------------------------------------------------------
__global__ __launch_bounds__(1024) void topk_sort(const unsigned* __restrict__ keys,
        const float* __restrict__ rois, float* __restrict__ bk,
        unsigned* __restrict__ tkey)
{
    __shared__ unsigned long long s64[2048];     // 16 KB, aliased as 2x u32[2048]
    __shared__ unsigned sc[2];
    __shared__ unsigned cntG, cntE;
    unsigned* histA = (unsigned*)&s64[0];
    unsigned* histB = histA + 2048;

    const int tid = threadIdx.x;
    const int n   = blockIdx.x;
    const unsigned* kp = keys + (size_t)n * HWA;

    unsigned need = PRE;
    unsigned b1 = 0, b2 = 0;

    for (int lvl = 0; lvl < 3; lvl++) {
        for (int i = tid; i < 2048; i += 1024) histA[i] = 0u;
        if (tid == 0) { cntG = 0u; cntE = 0u; }
        __syncthreads();
        for (int i = tid; i < HWA; i += 1024) {
            const unsigned k = kp[i];
            bool sel; unsigned bucket;
            if (lvl == 0)      { sel = true;                           bucket = k >> 21; }
            else if (lvl == 1) { sel = (k >> 21) == b1;                bucket = (k >> 10) & 2047u; }
            else               { sel = (k >> 10) == ((b1 << 11) | b2); bucket = k & 1023u; }
            if (sel) atomicAdd(&histA[bucket], 1u);
        }
        __syncthreads();
        unsigned *src = histA, *dst = histB;
        for (int ofs = 1; ofs < 2048; ofs <<= 1) {
            for (int i = tid; i < 2048; i += 1024)
                dst[i] = src[i] + ((i + ofs) < 2048 ? src[i + ofs] : 0u);
            __syncthreads();
            unsigned* t = src; src = dst; dst = t;
        }
        for (int i = tid; i < 2048; i += 1024) {
            const unsigned s = src[i];
            const unsigned sn = (i < 2047) ? src[i + 1] : 0u;
            if (s >= need && sn < need) { sc[0] = (unsigned)i; sc[1] = sn; }
        }
        __syncthreads();
        const unsigned b = sc[0];
        need -= sc[1];
        if (lvl == 0) b1 = b; else if (lvl == 1) b2 = b;
        else {
            // done: T known
            const unsigned T = (b1 << 21) | (b2 << 10) | b;
            const unsigned G = PRE - need;    // count strictly greater than T
            __syncthreads();
            for (int i = tid; i < 2048; i += 1024) s64[i] = 0ull;
            __syncthreads();
            for (int i = tid; i < HWA; i += 1024) {
                const unsigned k = kp[i];
                if (k > T) {
                    const unsigned p = atomicAdd(&cntG, 1u);
                    s64[p] = ((unsigned long long)k << 32) | (unsigned)(~(unsigned)i);
                } else if (k == T) {
                    const unsigned p = atomicAdd(&cntE, 1u);
                    if (G + p < 2048u)
                        s64[G + p] = ((unsigned long long)k << 32) | (unsigned)(~(unsigned)i);
                }
            }
            __syncthreads();
            // bitonic sort, descending; ties (equal key) -> ~idx desc -> idx asc
            for (unsigned ksz = 2; ksz <= 2048; ksz <<= 1) {
                for (unsigned jst = ksz >> 1; jst > 0; jst >>= 1) {
                    const unsigned i = (unsigned)tid;
                    const unsigned low = i & (jst - 1);
                    const unsigned l = ((i ^ low) << 1) | low;
                    const unsigned pr = l | jst;
                    const unsigned long long va = s64[l], vb = s64[pr];
                    const bool desc = (l & ksz) == 0;
                    if ((va < vb) == desc) { s64[l] = vb; s64[pr] = va; }
                    __syncthreads();
                }
            }
            const unsigned KEYNEG = ~__float_as_uint(-1e9f);
            for (int j = tid; j < 2048; j += 1024) {
                const unsigned long long v = s64[j];
                const unsigned key = (unsigned)(v >> 32);
                const unsigned idx = ~(unsigned)(v & 0xFFFFFFFFull);
                float4 box = {0.f, 0.f, 0.f, 0.f};
                if (key > KEYNEG) box = *(const float4*)&rois[((size_t)n * HWA + idx) * 4];
                *(float4*)&bk[((size_t)n * 2048 + j) * 4] = box;
                tkey[(size_t)n * 2048 + j] = (j < PRE) ? key : 0u;
            }
            return;
        }
        __syncthreads();
    }
}

// ---------------------------------------------------------------------------
// K4: greedy NMS (list is score-sorted: argmax(live)==first live) + output.
// ---------------------------------------------------------------------------
__global__ __launch_bounds__(256) void nms_out(const float* __restrict__ bk,
        const unsigned* __restrict__ tkey, float* __restrict__ out)
{
    __shared__ float sy1[2048], sx1[2048], sy2[2048], sx2[2048];
    __shared__ unsigned lv[2048];
    __shared__ unsigned sRed[4];

    const int tid = threadIdx.x;
    const int n   = blockIdx.x;
    const unsigned KEYNEG = ~__float_as_uint(-1e9f);

    for (int i = tid; i < 2048; i += 256) {
        float4 b = *(const float4*)&bk[((size_t)n * 2048 + i) * 4];
        sy1[i] = b.x; sx1[i] = b.y; sy2[i] = b.z; sx2[i] = b.w;
        lv[i] = (i < PRE) && (tkey[(size_t)n * 2048 + i] > KEYNEG);
    }
    if (n == 0 && tid == 0) out[9600] = 0.0f;   // rpn_loss
    __syncthreads();

    for (int it = 0; it < POST; it++) {
        unsigned cand = 0xFFFFFFFFu;
#pragma unroll
        for (int q = 0; q < 8; q++) {
            const int k = q * 256 + tid;         // stride-256: conflict-free
            if (lv[k]) cand = umin2(cand, (unsigned)k);
        }
#pragma unroll
        for (int off = 32; off; off >>= 1)
            cand = umin2(cand, (unsigned)__shfl_xor((int)cand, off, 64));
        if ((tid & 63) == 0) sRed[tid >> 6] = cand;
        __syncthreads();
        const unsigned j = umin2(umin2(sRed[0], sRed[1]), umin2(sRed[2], sRed[3]));

        float4 ob = {0.f, 0.f, 0.f, 0.f};
        if (j != 0xFFFFFFFFu) {
            const float jy1 = sy1[j], jx1 = sx1[j], jy2 = sy2[j], jx2 = sx2[j];
            const float a1 = (jy2 - jy1) * (jx2 - jx1);
#pragma unroll
            for (int q = 0; q < 8; q++) {
                const int k = q * 256 + tid;
                if (lv[k]) {
                    const float ty = fmaxf(jy1, sy1[k]), tx = fmaxf(jx1, sx1[k]);
                    const float by = fminf(jy2, sy2[k]), bx = fminf(jx2, sx2[k]);
                    const float ih = fmaxf(by - ty, 0.f), iw = fmaxf(bx - tx, 0.f);
                    const float inter = ih * iw;
                    const float a2 = (sy2[k] - sy1[k]) * (sx2[k] - sx1[k]);
                    const float iou = inter / ((a1 + a2) - inter);  // exact fp32 div
                    if (iou > 0.7f) lv[k] = 0u;   // suppresses j itself too (iou=1)
                }
            }
            ob = make_float4(jy1, jx1, jy2, jx2);
        }
        if (tid == 0) *(float4*)&out[((size_t)n * POST + it) * 4] = ob;
        __syncthreads();   // lv updates visible before next scan
    }
}

// ---------------------------------------------------------------------------
extern "C" void kernel_launch(void* const* d_in, const int* in_sizes, int n_in,
                              void* d_out, int out_size, void* d_ws, size_t ws_size,
                              hipStream_t stream)
{
    // d_in: 0=images(unused) 1=features 2=w_conv 3=b_conv 4=w_score 5=b_score 6=w_loc 7=b_loc
    const float* feat  = (const float*)d_in[1];
    const float* wconv = (const float*)d_in[2];
    const float* bconv = (const float*)d_in[3];
    const float* wsc   = (const float*)d_in[4];
    const float* bsc   = (const float*)d_in[5];
    const float* wlc   = (const float*)d_in[6];
    const float* blc   = (const float*)d_in[7];
    float* out = (float*)d_out;

    char* ws = (char*)d_ws;
    float*    h    = (float*)(ws);                   // 33,554,432 B
    float*    wt2  = (float*)(ws + 33554432);        //  2,359,296 B
    float*    rois = (float*)(ws + 35913728);        //  4,718,592 B
    unsigned* keys = (unsigned*)(ws + 40632320);     //  1,179,648 B
    float*    bk   = (float*)(ws + 41811968);        //    262,144 B
    unsigned* tkey = (unsigned*)(ws + 42074112);     //     65,536 B  (total ~42.1 MB)

    prep_wt2     <<<dim3(768),       dim3(256),  0, stream>>>(wconv, wt2);
    conv3x3_relu_v2<<<dim3(32, 4, 8), dim3(256), 0, stream>>>(feat, wt2, bconv, h);
    head_decode  <<<dim3(64, 8),     dim3(256),  0, stream>>>(h, wsc, bsc, wlc, blc, keys, rois);
    topk_sort    <<<dim3(8),         dim3(1024), 0, stream>>>(keys, rois, bk, tkey);
    nms_out      <<<dim3(8),         dim3(256),  0, stream>>>(bk, tkey, out);
}

// Round 4
// 1464.725 us; speedup vs baseline: 1.2583x; 1.2583x over previous
//
#include <hip/hip_runtime.h>
#include <stdint.h>

#define NIMG 8
#define HFW  64
#define HWA  36864     // 64*64*9
#define PRE  2000
#define POST 300

#define AS1 __attribute__((address_space(1)))
#define AS3 __attribute__((address_space(3)))

__device__ __forceinline__ unsigned keyOf(float f) {
    unsigned u = __float_as_uint(f);
    return (u & 0x80000000u) ? ~u : (u | 0x80000000u);
}
__device__ __forceinline__ unsigned umin2(unsigned a, unsigned b){ return a < b ? a : b; }

// ---------------------------------------------------------------------------
// K0: w_conv [co][ci][3][3] -> wt2 [ci][ky][cog(32)][co_l(8)*3+kx]  (24 f/group)
// ---------------------------------------------------------------------------
__global__ void prep_wt2(const float* __restrict__ w, float* __restrict__ wt2) {
    int t = blockIdx.x * 256 + threadIdx.x;      // t = (ci*3+ky)*256 + co
    if (t >= 256 * 3 * 256) return;
    int co = t & 255;
    int r  = t >> 8;            // ci*3+ky
    int ky = r % 3, ci = r / 3;
    const float* s = w + ((size_t)(co * 256 + ci)) * 9 + ky * 3;
    float* d = wt2 + (((size_t)(ci * 3 + ky)) * 32 + (co >> 3)) * 24 + (co & 7) * 3;
    d[0] = s[0]; d[1] = s[1]; d[2] = s[2];
}

// ---------------------------------------------------------------------------
// K1 v4: 3x3 conv SAME + bias + relu.  fp32 VALU, scalar-path weights,
// global_load_lds staging (no VGPR round-trip -> no spills), XCD-pinned images.
// block 256 thr; tile 8co x 16rows x 64px; thread 8co x 4px (32 acc).
// 1D grid 1024: n = b&7 (XCD pin), cog = (b>>3)&31, strip = b>>8.
// LDS: features only, double-buffered, 68-stride rows SHIFTED +1.
// ---------------------------------------------------------------------------
__global__ __launch_bounds__(256, 4) void conv3x3_relu_v4(const float* __restrict__ feat,
        const float* __restrict__ wt2, const float* __restrict__ bconv,
        float* __restrict__ h)
{
    __shared__ __align__(16) float sAll[2 * 4 * 18 * 68];   // 39,168 B

    const int tid  = threadIdx.x;
    const int lane = tid & 63;
    const int wv   = tid >> 6;          // wave 0..3 == staged ci slice
    const int b    = blockIdx.x;
    const int n    = b & 7;             // XCD-pinned image
    const int rem  = b >> 3;
    const int cog  = rem & 31;          // 0..31  (8 co each)
    const int y0   = (rem >> 5) << 4;   // 0,16,32,48
    const int pg   = tid & 15;
    const int px   = pg * 4;
    const int rr   = tid >> 4;          // 0..15 output row in strip

    const float* fb = feat + (size_t)n * 1048576;

    // zero both buffers once (halo cols + boundary rows rely on this persisting)
    {
        const float4 z4 = {0.f, 0.f, 0.f, 0.f};
        for (int i = tid * 4; i < 9792; i += 1024) *(float4*)&sAll[i] = z4;
    }
    __syncthreads();

    float acc[8][4];
#pragma unroll
    for (int a = 0; a < 8; a++)
#pragma unroll
        for (int c = 0; c < 4; c++) acc[a][c] = 0.0f;

    // stage ci slice (CK*4 + wv), rows r=0..17 (gy = y0-1+r), one row per
    // wave-instruction: LDS dest = uniform row base + lane*4B (HW), global
    // src per-lane.  Boundary rows skipped -> stay zero from the memset.
#define ISSUE_CK(CK, BUF) {                                                  \
        const float* _gb = fb + (size_t)((CK) * 4 + wv) * 4096 + lane;       \
        float* _lb = (BUF) + (wv * 18) * 68 + 1;                             \
        _Pragma("unroll")                                                    \
        for (int _t = 0; _t < 18; _t++) {                                    \
            const int _gy = y0 - 1 + _t;                                     \
            if (_gy >= 0 && _gy < 64)                                        \
                __builtin_amdgcn_global_load_lds(                            \
                    (const AS1 void*)(_gb + _gy * 64),                       \
                    (AS3 void*)(_lb + _t * 68), 4, 0, 0);                    \
        } }

    ISSUE_CK(0, sAll);
    asm volatile("s_waitcnt vmcnt(0)" ::: "memory");
    __syncthreads();

    for (int ck = 0; ck < 64; ck++) {
        const int ci0 = ck * 4;
        const float* bufc = sAll + (ck & 1) * 4896;
        float*       bufn = sAll + ((ck + 1) & 1) * 4896;

        if (ck < 63) ISSUE_CK(ck + 1, bufn);

        // compute: 12 (i,ky) steps x (2 ds_read_b128 + 24 scalar weights + 96 fmac)
        const float* rbase = bufc + rr * 68 + px;
#pragma unroll
        for (int i = 0; i < 4; i++) {
#pragma unroll
            for (int ky = 0; ky < 3; ky++) {
                const float* rowp = rbase + (i * 18 + ky) * 68;
                const float4 fA = *(const float4*)rowp;        // cols px-1..px+2
                const float4 fB = *(const float4*)(rowp + 4);  // cols px+3..px+6
                const float fc0 = fA.x, fc1 = fA.y, fc2 = fA.z, fc3 = fA.w;
                const float fc4 = fB.x, fc5 = fB.y;
                const float* wq = wt2 + (((size_t)(ci0 + i) * 3 + ky) * 32 + cog) * 24;
#pragma unroll
                for (int cc = 0; cc < 8; cc++) {
                    const float w0 = wq[cc * 3 + 0], w1 = wq[cc * 3 + 1], w2 = wq[cc * 3 + 2];
                    acc[cc][0] = fmaf(w0, fc0, acc[cc][0]);
                    acc[cc][0] = fmaf(w1, fc1, acc[cc][0]);
                    acc[cc][0] = fmaf(w2, fc2, acc[cc][0]);
                    acc[cc][1] = fmaf(w0, fc1, acc[cc][1]);
                    acc[cc][1] = fmaf(w1, fc2, acc[cc][1]);
                    acc[cc][1] = fmaf(w2, fc3, acc[cc][1]);
                    acc[cc][2] = fmaf(w0, fc2, acc[cc][2]);
                    acc[cc][2] = fmaf(w1, fc3, acc[cc][2]);
                    acc[cc][2] = fmaf(w2, fc4, acc[cc][2]);
                    acc[cc][3] = fmaf(w0, fc3, acc[cc][3]);
                    acc[cc][3] = fmaf(w1, fc4, acc[cc][3]);
                    acc[cc][3] = fmaf(w2, fc5, acc[cc][3]);
                }
            }
        }

        asm volatile("s_waitcnt vmcnt(0)" ::: "memory");
        __syncthreads();
    }
#undef ISSUE_CK

    // epilogue: bias + relu + store
#pragma unroll
    for (int cc = 0; cc < 8; cc++) {
        const int co = cog * 8 + cc;
        const float bb = bconv[co];
        float4 o;
        o.x = fmaxf(acc[cc][0] + bb, 0.f);
        o.y = fmaxf(acc[cc][1] + bb, 0.f);
        o.z = fmaxf(acc[cc][2] + bb, 0.f);
        o.w = fmaxf(acc[cc][3] + bb, 0.f);
        *(float4*)(h + ((size_t)(n * 256 + co)) * 4096 + (y0 + rr) * 64 + px) = o;
    }
}

// ---------------------------------------------------------------------------
// K2: 1x1 heads (scores 9, locs 36) + box decode + clip + validity -> keys/rois
// 1D grid 512: n = b&7 (XCD pin), y = b>>3.
// ---------------------------------------------------------------------------
__global__ __launch_bounds__(256) void head_decode(const float* __restrict__ h,
        const float* __restrict__ wsc, const float* __restrict__ bsc,
        const float* __restrict__ wlc, const float* __restrict__ blc,
        unsigned* __restrict__ keys, float* __restrict__ rois)
{
    __shared__ float sH[128][64];
    __shared__ float sOut[64][49];

    const int tid = threadIdx.x;
    const int n   = blockIdx.x & 7;
    const int y   = blockIdx.x >> 3;
    const int px  = tid & 63;
    const int sl  = tid >> 6;             // == wave id
    const int o0  = sl * 12;

    const float* wp[12];
#pragma unroll
    for (int j = 0; j < 12; j++) {
        const int o = o0 + j;
        wp[j] = (o < 36) ? (wlc + (size_t)o * 256)
                         : ((o < 45) ? (wsc + (size_t)(o - 36) * 256) : wsc);
    }
    float r[12];
#pragma unroll
    for (int j = 0; j < 12; j++) r[j] = 0.0f;

    const float* hb = h + (size_t)n * 1048576 + y * 64;
    for (int half = 0; half < 2; half++) {
        for (int task = tid; task < 2048; task += 256) {
            const int c = task >> 4, x4 = (task & 15) << 2;
            *(float4*)&sH[c][x4] =
                *(const float4*)(hb + (size_t)(half * 128 + c) * 4096 + x4);
        }
        __syncthreads();
        for (int c4 = 0; c4 < 128; c4 += 4) {
            const float h0 = sH[c4][px], h1 = sH[c4 + 1][px];
            const float h2 = sH[c4 + 2][px], h3 = sH[c4 + 3][px];
#pragma unroll
            for (int j = 0; j < 12; j++) {
                float4 w = *(const float4*)(wp[j] + half * 128 + c4);
                r[j] = fmaf(h0, w.x, r[j]); r[j] = fmaf(h1, w.y, r[j]);
                r[j] = fmaf(h2, w.z, r[j]); r[j] = fmaf(h3, w.w, r[j]);
            }
        }
        __syncthreads();
    }
#pragma unroll
    for (int j = 0; j < 12; j++) {
        const int o = o0 + j;
        if (o < 45) {
            const float bias = (o < 36) ? blc[o] : bsc[o - 36];
            sOut[px][o] = r[j] + bias;
        }
    }
    __syncthreads();

    // decode (replicate reference fp32 op order; no contraction)
    for (int a = sl; a < 9; a += 4) {
        const float s  = sOut[px][36 + a];
        const float dy = sOut[px][a * 4 + 0], dx = sOut[px][a * 4 + 1];
        const float dh = sOut[px][a * 4 + 2], dw = sOut[px][a * 4 + 3];
        const int si = a / 3, ri = a - si * 3;
        const float scale = (si == 0) ? 64.f : ((si == 1) ? 128.f : 256.f);
        const float rat   = (ri == 0) ? 0.5f : ((ri == 1) ? 1.f : 2.f);
        const float sq = __fsqrt_rn(rat);
        const float hs = __fmul_rn(scale, sq);
        const float ws = __fdiv_rn(scale, sq);
        const float cy = (y  + 0.5f) * 16.0f;   // exact
        const float cx = (px + 0.5f) * 16.0f;
        const float y1 = __fsub_rn(cy, __fmul_rn(hs, 0.5f));
        const float x1 = __fsub_rn(cx, __fmul_rn(ws, 0.5f));
        const float y2 = __fadd_rn(cy, __fmul_rn(hs, 0.5f));
        const float x2 = __fadd_rn(cx, __fmul_rn(ws, 0.5f));
        const float ah = __fsub_rn(y2, y1), aw = __fsub_rn(x2, x1);
        const float acy = __fadd_rn(y1, __fmul_rn(0.5f, ah));
        const float acx = __fadd_rn(x1, __fmul_rn(0.5f, aw));
        const float pcy = __fadd_rn(__fmul_rn(dy, ah), acy);
        const float pcx = __fadd_rn(__fmul_rn(dx, aw), acx);
        const float ph  = __fmul_rn(expf(dh), ah);
        const float pw  = __fmul_rn(expf(dw), aw);
        float by1 = __fsub_rn(pcy, __fmul_rn(0.5f, ph));
        float bx1 = __fsub_rn(pcx, __fmul_rn(0.5f, pw));
        float by2 = __fadd_rn(pcy, __fmul_rn(0.5f, ph));
        float bx2 = __fadd_rn(pcx, __fmul_rn(0.5f, pw));
        by1 = fminf(fmaxf(by1, 0.f), 1024.f); by2 = fminf(fmaxf(by2, 0.f), 1024.f);
        bx1 = fminf(fmaxf(bx1, 0.f), 1024.f); bx2 = fminf(fmaxf(bx2, 0.f), 1024.f);
        const float bh = __fsub_rn(by2, by1), bw = __fsub_rn(bx2, bx1);
        const bool valid = (bh >= 16.f) && (bw >= 16.f) && (s >= 0.f);
        const float sm = valid ? s : -1e9f;
        const int idx = (y * 64 + px) * 9 + a;
        keys[(size_t)n * HWA + idx] = keyOf(sm);
        float4 bxv = {by1, bx1, by2, bx2};
        *(float4*)&rois[((size_t)n * HWA + idx) * 4] = bxv;
    }
}

// ---------------------------------------------------------------------------
// K3: exact top-2000 sorted (key desc, idx asc) via 3-level histogram select
//     + compaction + 2048 bitonic sort.  1 block (1024 thr) per image.
//     Scans vectorized uint4.
// ---------------------------------------------------------------------------
__global__ __launch_bounds__(1024) void topk_sort(const unsigned* __restrict__ keys,
        const float* __restrict__ rois, float* __restrict__ bk,
        unsigned* __restrict__ tkey)
{
    __shared__ unsigned long long s64[2048];     // 16 KB, aliased as 2x u32[2048]
    __shared__ unsigned sc[2];
    __shared__ unsigned cntG, cntE;
    unsigned* histA = (unsigned*)&s64[0];
    unsigned* histB = histA + 2048;

    const int tid = threadIdx.x;
    const int n   = blockIdx.x;
    const unsigned* kp = keys + (size_t)n * HWA;
    const uint4* kp4 = (const uint4*)kp;

    unsigned need = PRE;
    unsigned b1 = 0, b2 = 0;

    for (int lvl = 0; lvl < 3; lvl++) {
        for (int i = tid; i < 2048; i += 1024) histA[i] = 0u;
        if (tid == 0) { cntG = 0u; cntE = 0u; }
        __syncthreads();
        for (int i = tid; i < 9216; i += 1024) {
            const uint4 kv = kp4[i];
#pragma unroll
            for (int c = 0; c < 4; c++) {
                const unsigned k = (&kv.x)[c];
                bool sel; unsigned bucket;
                if (lvl == 0)      { sel = true;                           bucket = k >> 21; }
                else if (lvl == 1) { sel = (k >> 21) == b1;                bucket = (k >> 10) & 2047u; }
                else               { sel = (k >> 10) == ((b1 << 11) | b2); bucket = k & 1023u; }
                if (sel) atomicAdd(&histA[bucket], 1u);
            }
        }
        __syncthreads();
        unsigned *src = histA, *dst = histB;
        for (int ofs = 1; ofs < 2048; ofs <<= 1) {
            for (int i = tid; i < 2048; i += 1024)
                dst[i] = src[i] + ((i + ofs) < 2048 ? src[i + ofs] : 0u);
            __syncthreads();
            unsigned* t = src; src = dst; dst = t;
        }
        for (int i = tid; i < 2048; i += 1024) {
            const unsigned s = src[i];
            const unsigned sn = (i < 2047) ? src[i + 1] : 0u;
            if (s >= need && sn < need) { sc[0] = (unsigned)i; sc[1] = sn; }
        }
        __syncthreads();
        const unsigned b = sc[0];
        need -= sc[1];
        if (lvl == 0) b1 = b; else if (lvl == 1) b2 = b;
        else {
            // done: T known
            const unsigned T = (b1 << 21) | (b2 << 10) | b;
            const unsigned G = PRE - need;    // count strictly greater than T
            __syncthreads();
            for (int i = tid; i < 2048; i += 1024) s64[i] = 0ull;
            __syncthreads();
            for (int i = tid; i < 9216; i += 1024) {
                const uint4 kv = kp4[i];
#pragma unroll
                for (int c = 0; c < 4; c++) {
                    const unsigned k = (&kv.x)[c];
                    const unsigned ei = (unsigned)(i * 4 + c);
                    if (k > T) {
                        const unsigned p = atomicAdd(&cntG, 1u);
                        s64[p] = ((unsigned long long)k << 32) | (unsigned)(~ei);
                    } else if (k == T) {
                        const unsigned p = atomicAdd(&cntE, 1u);
                        if (G + p < 2048u)
                            s64[G + p] = ((unsigned long long)k << 32) | (unsigned)(~ei);
                    }
                }
            }
            __syncthreads();
            // bitonic sort, descending; ties (equal key) -> ~idx desc -> idx asc
            for (unsigned ksz = 2; ksz <= 2048; ksz <<= 1) {
                for (unsigned jst = ksz >> 1; jst > 0; jst >>= 1) {
                    const unsigned i = (unsigned)tid;
                    const unsigned low = i & (jst - 1);
                    const unsigned l = ((i ^ low) << 1) | low;
                    const unsigned pr = l | jst;
                    const unsigned long long va = s64[l], vb = s64[pr];
                    const bool desc = (l & ksz) == 0;
                    if ((va < vb) == desc) { s64[l] = vb; s64[pr] = va; }
                    __syncthreads();
                }
            }
            const unsigned KEYNEG = ~__float_as_uint(-1e9f);
            for (int j = tid; j < 2048; j += 1024) {
                const unsigned long long v = s64[j];
                const unsigned key = (unsigned)(v >> 32);
                const unsigned idx = ~(unsigned)(v & 0xFFFFFFFFull);
                float4 box = {0.f, 0.f, 0.f, 0.f};
                if (key > KEYNEG) box = *(const float4*)&rois[((size_t)n * HWA + idx) * 4];
                *(float4*)&bk[((size_t)n * 2048 + j) * 4] = box;
                tkey[(size_t)n * 2048 + j] = (j < PRE) ? key : 0u;
            }
            return;
        }
        __syncthreads();
    }
}

// ---------------------------------------------------------------------------
// K4: greedy NMS with monotone first-live base (dead prefix never rescanned;
// IoU loop starts at j).  1 block (256 thr) per image.
// ---------------------------------------------------------------------------
__global__ __launch_bounds__(256) void nms_out(const float* __restrict__ bk,
        const unsigned* __restrict__ tkey, float* __restrict__ out)
{
    __shared__ float sy1[2048], sx1[2048], sy2[2048], sx2[2048];
    __shared__ unsigned lv[2048];
    __shared__ unsigned sRed[4];

    const int tid = threadIdx.x;
    const int n   = blockIdx.x;
    const unsigned KEYNEG = ~__float_as_uint(-1e9f);
    const unsigned INF = 0xFFFFFFFFu;

    for (int i = tid; i < 2048; i += 256) {
        float4 b = *(const float4*)&bk[((size_t)n * 2048 + i) * 4];
        sy1[i] = b.x; sx1[i] = b.y; sy2[i] = b.z; sx2[i] = b.w;
        lv[i] = (i < PRE) && (tkey[(size_t)n * 2048 + i] > KEYNEG);
    }
    if (n == 0 && tid == 0) out[9600] = 0.0f;   // rpn_loss
    __syncthreads();

    unsigned base = 0;
    for (int it = 0; it < POST; it++) {
        // first live index >= base (live set only shrinks -> base monotone)
        unsigned j = INF;
        for (unsigned wstart = base; wstart < 2048u; wstart += 256u) {
            const unsigned k = wstart + (unsigned)tid;
            unsigned c = (k < 2048u && lv[k]) ? k : INF;
#pragma unroll
            for (int off = 32; off; off >>= 1)
                c = umin2(c, (unsigned)__shfl_xor((int)c, off, 64));
            __syncthreads();                 // protect sRed reuse
            if ((tid & 63) == 0) sRed[tid >> 6] = c;
            __syncthreads();
            j = umin2(umin2(sRed[0], sRed[1]), umin2(sRed[2], sRed[3]));
            if (j != INF) break;             // uniform
        }

        float4 ob = {0.f, 0.f, 0.f, 0.f};
        if (j != INF) {
            const float jy1 = sy1[j], jx1 = sx1[j], jy2 = sy2[j], jx2 = sx2[j];
            const float a1 = (jy2 - jy1) * (jx2 - jx1);
            for (unsigned k = j + (unsigned)tid; k < 2048u; k += 256u) {
                if (lv[k]) {
                    const float ty = fmaxf(jy1, sy1[k]), tx = fmaxf(jx1, sx1[k]);
                    const float by = fminf(jy2, sy2[k]), bx = fminf(jx2, sx2[k]);
                    const float ih = fmaxf(by - ty, 0.f), iw = fmaxf(bx - tx, 0.f);
                    const float inter = ih * iw;
                    const float a2 = (sy2[k] - sy1[k]) * (sx2[k] - sx1[k]);
                    const float iou = inter / ((a1 + a2) - inter);  // exact fp32 div
                    if (iou > 0.7f) lv[k] = 0u;   // suppresses j itself (iou=1)
                }
            }
            ob = make_float4(jy1, jx1, jy2, jx2);
            base = j + 1;
        } else {
            base = 2048u;
        }
        if (tid == 0) *(float4*)&out[((size_t)n * POST + it) * 4] = ob;
        __syncthreads();   // lv updates visible before next scan
    }
}

// ---------------------------------------------------------------------------
extern "C" void kernel_launch(void* const* d_in, const int* in_sizes, int n_in,
                              void* d_out, int out_size, void* d_ws, size_t ws_size,
                              hipStream_t stream)
{
    // d_in: 0=images(unused) 1=features 2=w_conv 3=b_conv 4=w_score 5=b_score 6=w_loc 7=b_loc
    const float* feat  = (const float*)d_in[1];
    const float* wconv = (const float*)d_in[2];
    const float* bconv = (const float*)d_in[3];
    const float* wsc   = (const float*)d_in[4];
    const float* bsc   = (const float*)d_in[5];
    const float* wlc   = (const float*)d_in[6];
    const float* blc   = (const float*)d_in[7];
    float* out = (float*)d_out;

    char* ws = (char*)d_ws;
    float*    h    = (float*)(ws);                   // 33,554,432 B
    float*    wt2  = (float*)(ws + 33554432);        //  2,359,296 B
    float*    rois = (float*)(ws + 35913728);        //  4,718,592 B
    unsigned* keys = (unsigned*)(ws + 40632320);     //  1,179,648 B
    float*    bk   = (float*)(ws + 41811968);        //    262,144 B
    unsigned* tkey = (unsigned*)(ws + 42074112);     //     65,536 B  (total ~42.1 MB)

    prep_wt2       <<<dim3(768),  dim3(256),  0, stream>>>(wconv, wt2);
    conv3x3_relu_v4<<<dim3(1024), dim3(256),  0, stream>>>(feat, wt2, bconv, h);
    head_decode    <<<dim3(512),  dim3(256),  0, stream>>>(h, wsc, bsc, wlc, blc, keys, rois);
    topk_sort      <<<dim3(8),    dim3(1024), 0, stream>>>(keys, rois, bk, tkey);
    nms_out        <<<dim3(8),    dim3(256),  0, stream>>>(bk, tkey, out);
}